// Round 4
// baseline (4654.375 us; speedup 1.0000x reference)
//
#include <hip/hip_runtime.h>
#include <hip/hip_bf16.h>

typedef float f32;
typedef __hip_bfloat16 bf16;
typedef unsigned int u32;
typedef unsigned short u16;

#define T_LEN 128
#define B_SZ  64
#define E_DIM 512
#define U_DIM 1024
#define G3    3072
#define BTU   (B_SZ * T_LEN * U_DIM)

typedef __attribute__((ext_vector_type(8))) __bf16 bf16x8;
typedef __attribute__((ext_vector_type(8))) u16  us8;
typedef __attribute__((ext_vector_type(4))) f32  f32x4;

union F8 { us8 u; bf16x8 b; };

// workspace layout (bytes)
#define WS_USW 0u            // bf16 bits [256 blk][2 plane][24 row][1024 k] swizzled = 25165824 B
#define WS_HQ  25165824u     // u32 [2 buf][2 dir][1024 u][64 b] packed (hi | lo<<16) = 1048576 B
#define WS_XG  26214400u     // bf16 [2][128][3072][64] = 100663296 B
#define WS_BAR 126877696u    // u32 barrier counter

#define LDS_BYTES 106496     // 96 KB U image + 8 KB reduce

__device__ __forceinline__ u32 f32_to_bf16_rne(f32 x) {
  u32 b = __float_as_uint(x);
  return (b + 0x7fffu + ((b >> 16) & 1u)) >> 16;
}

// ---------------- U transpose + hi/lo split + per-block swizzled image ----------------
__global__ __launch_bounds__(256) void transpose_split(
    const f32* __restrict__ Uf, const f32* __restrict__ Ub, u16* __restrict__ USW)
{
  __shared__ f32 tile[32][33];
  const int d = blockIdx.z;
  const f32* Uw = d ? Ub : Uf;
  const int c0 = blockIdx.x * 32;
  const int k0 = blockIdx.y * 32;
  const int tx = threadIdx.x & 31;
  const int ty = threadIdx.x >> 5;
#pragma unroll
  for (int i = 0; i < 4; i++) {
    int kl = ty + i * 8;
    tile[kl][tx] = Uw[(size_t)(k0 + kl) * G3 + c0 + tx];
  }
  __syncthreads();
#pragma unroll
  for (int i = 0; i < 4; i++) {
    int cl = ty + i * 8;
    int c  = c0 + cl;
    f32 val = tile[tx][cl];
    int g = c >> 10, u = c & 1023;
    int blk = d * 128 + (u >> 3);
    int r   = g * 8 + (u & 7);
    u32 hib = f32_to_bf16_rne(val);
    f32 rem = val - __uint_as_float(hib << 16);
    u32 lob = f32_to_bf16_rne(rem);
    int k = k0 + tx;
    int slot = (k >> 3) ^ (r & 7);
    size_t base = ((size_t)blk * 2) * (24 * 1024);
    size_t off  = (size_t)r * 1024 + slot * 8 + (k & 7);
    USW[base + off] = (u16)hib;
    USW[base + (size_t)24 * 1024 + off] = (u16)lob;
  }
}

// ---------------- input projection (unchanged): XG[d][s][col][b] ----------------
__global__ __launch_bounds__(256) void xg_gemm(
    const int* __restrict__ tokens, const f32* __restrict__ emb,
    const f32* __restrict__ Wf, const f32* __restrict__ bif,
    const f32* __restrict__ Wb, const f32* __restrict__ bib,
    bf16* __restrict__ XG)
{
  __shared__ f32 As[8][128];
  __shared__ f32 Bs[8][128];
  __shared__ int tok_s[128];

  const int tid = threadIdx.x;
  const int n0 = blockIdx.x * 128;
  const int m0 = blockIdx.y * 128;
  const int dir = (m0 >= T_LEN * B_SZ) ? 1 : 0;
  const f32* W  = dir ? Wb : Wf;
  const f32* bi = dir ? bib : bif;

  if (tid < 128) {
    int mm = m0 + tid - dir * (T_LEN * B_SZ);
    int s = mm >> 6, b = mm & 63;
    int t_orig = dir ? s : (T_LEN - 1 - s);
    tok_s[tid] = tokens[b * T_LEN + t_orig];
  }
  __syncthreads();

  const int lr = tid >> 1;
  const int lh = (tid & 1) * 4;
  const int bk = tid >> 5;
  const int bn = (tid & 31) * 4;
  const f32* arow = emb + (size_t)tok_s[lr] * E_DIM + lh;
  const f32* brow = W + (size_t)bk * G3 + n0 + bn;

  const int tm = tid >> 4;
  const int tn = tid & 15;

  f32 acc[8][8];
#pragma unroll
  for (int i = 0; i < 8; i++)
#pragma unroll
    for (int j = 0; j < 8; j++) acc[i][j] = 0.f;

  for (int k0 = 0; k0 < E_DIM; k0 += 8) {
    float4 av = *(const float4*)(arow + k0);
    float4 bv = *(const float4*)(brow + (size_t)k0 * G3);
    __syncthreads();
    As[lh + 0][lr] = av.x;
    As[lh + 1][lr] = av.y;
    As[lh + 2][lr] = av.z;
    As[lh + 3][lr] = av.w;
    *(float4*)&Bs[bk][bn] = bv;
    __syncthreads();
#pragma unroll
    for (int kk = 0; kk < 8; kk++) {
      float4 a0 = *(float4*)&As[kk][tm * 4];
      float4 a1 = *(float4*)&As[kk][64 + tm * 4];
      float4 b0 = *(float4*)&Bs[kk][tn * 4];
      float4 b1 = *(float4*)&Bs[kk][64 + tn * 4];
      f32 am[8] = {a0.x,a0.y,a0.z,a0.w,a1.x,a1.y,a1.z,a1.w};
      f32 bb[8] = {b0.x,b0.y,b0.z,b0.w,b1.x,b1.y,b1.z,b1.w};
#pragma unroll
      for (int i = 0; i < 8; i++)
#pragma unroll
        for (int j = 0; j < 8; j++)
          acc[i][j] += am[i] * bb[j];
    }
  }

  f32 biv[8];
#pragma unroll
  for (int j = 0; j < 8; j++) {
    int nloc = tn * 4 + (j & 3) + (j >> 2) * 64;
    biv[j] = bi[n0 + nloc];
  }
#pragma unroll
  for (int i = 0; i < 8; i++) {
    int mloc = tm * 4 + (i & 3) + (i >> 2) * 64;
    int mm = m0 + mloc - dir * (T_LEN * B_SZ);
    int s = mm >> 6, b = mm & 63;
    size_t rowbase = ((size_t)(dir * T_LEN + s) * G3) * B_SZ + b;
#pragma unroll
    for (int j = 0; j < 8; j++) {
      int nloc = tn * 4 + (j & 3) + (j >> 2) * 64;
      XG[rowbase + (size_t)(n0 + nloc) * B_SZ] = __float2bfloat16(acc[i][j] + biv[j]);
    }
  }
}

// ---------------- persistent recurrence: 256 blocks (1/CU), all 128 steps ----------------
// block = (dir, 8 u's). U image staged to LDS ONCE; per step: MFMA over K=1024,
// LDS k-half reduce, gate epilogue, device-scope arrive/spin barrier.
__global__ __launch_bounds__(512) void gru_persist(
    const u16* __restrict__ USW,
    u32* __restrict__ Hq,            // [2 buf][2 dir][1024][64] packed bf16 pairs
    const u16* __restrict__ XG,      // bf16 bits [2][128][3072][64]
    const f32* __restrict__ bhf, const f32* __restrict__ bhb,
    f32* __restrict__ out,
    u32* __restrict__ bar)
{
  extern __shared__ u16 Us[];        // [2][24][1024] swizzled (96 KB) + reduce region (8 KB)
  const int blk = blockIdx.x;
  const int dir = blk >> 7;
  const int su  = (blk & 127) * 8;
  const int tid = threadIdx.x;
  const int lane = tid & 63;
  const int w  = tid >> 6;
  const int nw = w & 3, kw = w >> 2;

  // stage per-block U image once (swizzle baked into global layout)
  {
    const us8* src = (const us8*)(USW + (size_t)blk * (2 * 24 * 1024));
    us8* dst = (us8*)Us;
    for (int i = tid; i < 6144; i += 512) dst[i] = src[i];
  }

  const int bb = nw * 16 + (lane & 15);
  const int ko = (lane >> 4) * 8;
  const int r0 = lane & 15;
  const int r1t = 16 + (lane & 15);
  const int r1 = r1t > 23 ? 23 : r1t;

  const int rb_h0 = (0 * 24 + r0) * 2048;
  const int rb_l0 = (1 * 24 + r0) * 2048;
  const int rb_h1 = (0 * 24 + r1) * 2048;
  const int rb_l1 = (1 * 24 + r1) * 2048;
  const int sw0 = r0 & 7, sw1 = r1 & 7;

  f32* red = (f32*)(Us + 49152);     // [4][64][8] f32 = 8 KB
  const f32* bh = dir ? bhb : bhf;

  __syncthreads();

  for (int s = 0; s < T_LEN; s++) {
    const u32* Hin  = Hq + (size_t)((s & 1) * 2 + dir) * (U_DIM * B_SZ);
    u32*       Hout = Hq + (size_t)(((s + 1) & 1) * 2 + dir) * (U_DIM * B_SZ);

    f32x4 acc0 = {0.f, 0.f, 0.f, 0.f};
    f32x4 acc1 = {0.f, 0.f, 0.f, 0.f};

    if (s) {
      for (int ks = 0; ks < 16; ks++) {
        const int kb = kw * 512 + ks * 32;
        const int slot = (kb >> 3) + (lane >> 4);
        F8 ah0, al0, ah1, al1;
        ah0.u = *(const us8*)((const char*)Us + rb_h0 + ((slot ^ sw0) << 4));
        al0.u = *(const us8*)((const char*)Us + rb_l0 + ((slot ^ sw0) << 4));
        ah1.u = *(const us8*)((const char*)Us + rb_h1 + ((slot ^ sw1) << 4));
        al1.u = *(const us8*)((const char*)Us + rb_l1 + ((slot ^ sw1) << 4));

        const int kbase = kb + ko;
        u32 wd[8];
#pragma unroll
        for (int e = 0; e < 8; e++) wd[e] = Hin[(size_t)(kbase + e) * B_SZ + bb];
        F8 bh_hi, bh_lo;
#pragma unroll
        for (int e = 0; e < 8; e++) {
          bh_hi.u[e] = (u16)(wd[e] & 0xffffu);
          bh_lo.u[e] = (u16)(wd[e] >> 16);
        }
        acc0 = __builtin_amdgcn_mfma_f32_16x16x32_bf16(ah0.b, bh_hi.b, acc0, 0, 0, 0);
        acc0 = __builtin_amdgcn_mfma_f32_16x16x32_bf16(ah0.b, bh_lo.b, acc0, 0, 0, 0);
        acc0 = __builtin_amdgcn_mfma_f32_16x16x32_bf16(al0.b, bh_hi.b, acc0, 0, 0, 0);
        acc1 = __builtin_amdgcn_mfma_f32_16x16x32_bf16(ah1.b, bh_hi.b, acc1, 0, 0, 0);
        acc1 = __builtin_amdgcn_mfma_f32_16x16x32_bf16(ah1.b, bh_lo.b, acc1, 0, 0, 0);
        acc1 = __builtin_amdgcn_mfma_f32_16x16x32_bf16(al1.b, bh_hi.b, acc1, 0, 0, 0);
      }
    }

    __syncthreads();
    if (kw == 1) {
      f32* p = red + (size_t)(nw * 64 + lane) * 8;
      *(f32x4*)p = acc0;
      *(f32x4*)(p + 4) = acc1;
    }
    __syncthreads();
    if (kw == 0) {
      const f32* p = red + (size_t)(nw * 64 + lane) * 8;
      f32x4 o0 = *(const f32x4*)p;
      f32x4 o1 = *(const f32x4*)(p + 4);
#pragma unroll
      for (int i = 0; i < 4; i++) { acc0[i] += o0[i]; acc1[i] += o1[i]; }

      f32 racc[4];
#pragma unroll
      for (int j = 0; j < 4; j++) racc[j] = __shfl_xor(acc0[j], 32);

      if (lane < 32) {
        const size_t xgb = ((size_t)(dir * T_LEN + s) * G3) * B_SZ + bb;
        const int t = dir ? (T_LEN - 1 - s) : s;
#pragma unroll
        for (int j = 0; j < 4; j++) {
          const int ul = (lane >> 4) * 4 + j;
          const int u  = su + ul;
          f32 hz = acc0[j] + bh[u];
          f32 hr = racc[j] + bh[1024 + u];
          f32 hh = acc1[j] + bh[2048 + u];
          f32 xz = __uint_as_float((u32)XG[xgb + (size_t)u * B_SZ] << 16);
          f32 xr = __uint_as_float((u32)XG[xgb + (size_t)(1024 + u) * B_SZ] << 16);
          f32 xh = __uint_as_float((u32)XG[xgb + (size_t)(2048 + u) * B_SZ] << 16);

          u32 hw = s ? Hin[(size_t)u * B_SZ + bb] : 0u;
          f32 hold = __uint_as_float(hw << 16) + __uint_as_float(hw & 0xffff0000u);

          f32 z  = 1.f / (1.f + expf(-(xz + hz)));
          f32 r  = 1.f / (1.f + expf(-(xr + hr)));
          f32 hc = tanhf(xh + r * hh);
          f32 hnew = z * hold + (1.f - z) * hc;

          u32 hib = f32_to_bf16_rne(hnew);
          f32 rem = hnew - __uint_as_float(hib << 16);
          u32 lob = f32_to_bf16_rne(rem);
          Hout[(size_t)u * B_SZ + bb] = hib | (lob << 16);

          size_t oidx = ((size_t)bb * T_LEN + t) * U_DIM + u;
          if (s < 64) out[oidx] = hnew;
          else        out[oidx] += hnew;

          if (s == T_LEN - 1)
            out[(size_t)BTU + (size_t)bb * 2048 + dir * 1024 + u] = hnew;
        }
      }
    }

    // grid-wide barrier: release stores, arrive, spin, acquire
    __syncthreads();
    if (tid == 0) {
      __threadfence();
      __hip_atomic_fetch_add(bar, 1u, __ATOMIC_RELAXED, __HIP_MEMORY_SCOPE_AGENT);
      const u32 tgt = 256u * (u32)(s + 1);
      while (__hip_atomic_load(bar, __ATOMIC_RELAXED, __HIP_MEMORY_SCOPE_AGENT) < tgt)
        __builtin_amdgcn_s_sleep(2);
      __threadfence();
    }
    __syncthreads();
  }
}

extern "C" void kernel_launch(void* const* d_in, const int* in_sizes, int n_in,
                              void* d_out, int out_size, void* d_ws, size_t ws_size,
                              hipStream_t stream) {
  (void)in_sizes; (void)n_in; (void)out_size; (void)ws_size;
  const int* tokens = (const int*)d_in[0];
  const f32* emb = (const f32*)d_in[1];
  const f32* Wf  = (const f32*)d_in[2];
  const f32* Uf  = (const f32*)d_in[3];
  const f32* bif = (const f32*)d_in[4];
  const f32* bhf = (const f32*)d_in[5];
  const f32* Wb  = (const f32*)d_in[6];
  const f32* Ub  = (const f32*)d_in[7];
  const f32* bib = (const f32*)d_in[8];
  const f32* bhb = (const f32*)d_in[9];

  char* ws = (char*)d_ws;
  u16*  USW = (u16*)(ws + WS_USW);
  u32*  Hq  = (u32*)(ws + WS_HQ);
  bf16* XG  = (bf16*)(ws + WS_XG);
  u32*  bar = (u32*)(ws + WS_BAR);
  f32*  out = (f32*)d_out;

  hipMemsetAsync(bar, 0, sizeof(u32), stream);
  transpose_split<<<dim3(96, 32, 2), 256, 0, stream>>>(Uf, Ub, USW);
  xg_gemm<<<dim3(24, 128), 256, 0, stream>>>(tokens, emb, Wf, bif, Wb, bib, XG);

  hipFuncSetAttribute((const void*)gru_persist,
                      hipFuncAttributeMaxDynamicSharedMemorySize, LDS_BYTES);
  const u16* usw_a = USW;
  u32*       hq_a  = Hq;
  const u16* xg_a  = (const u16*)XG;
  const f32* bhf_a = bhf;
  const f32* bhb_a = bhb;
  f32*       out_a = out;
  u32*       bar_a = bar;
  void* kargs[] = { (void*)&usw_a, (void*)&hq_a, (void*)&xg_a,
                    (void*)&bhf_a, (void*)&bhb_a, (void*)&out_a, (void*)&bar_a };
  hipLaunchCooperativeKernel((const void*)gru_persist, dim3(256), dim3(512),
                             kargs, LDS_BYTES, stream);
}

// Round 5
// 2582.543 us; speedup vs baseline: 1.8022x; 1.8022x over previous
//
#include <hip/hip_runtime.h>
#include <hip/hip_bf16.h>

typedef float f32;
typedef __hip_bfloat16 bf16;
typedef unsigned int u32;
typedef unsigned short u16;

#define T_LEN 128
#define B_SZ  64
#define E_DIM 512
#define U_DIM 1024
#define G3    3072
#define BTU   (B_SZ * T_LEN * U_DIM)

typedef __attribute__((ext_vector_type(8))) __bf16 bf16x8;
typedef __attribute__((ext_vector_type(8))) u16  us8;
typedef __attribute__((ext_vector_type(4))) u16  us4;
typedef __attribute__((ext_vector_type(4))) f32  f32x4;

union F8 { us8 u; bf16x8 b; };

// workspace layout (bytes)
#define WS_USW 0u            // bf16 bits [256 blk][2 plane][24 row][1024 k] swizzled = 25165824 B
#define WS_HQ  25165824u     // u16 [2 buf][2 plane][2 dir][64 b][1024 k] = 524288 B
#define WS_XG  26214400u     // bf16 [2][128][64 b][3072 col] = 100663296 B

#define LDS_BYTES (98304 + 24576)   // 96 KB U image + 24 KB reduce

__device__ __forceinline__ u32 f32_to_bf16_rne(f32 x) {
  u32 b = __float_as_uint(x);
  return (b + 0x7fffu + ((b >> 16) & 1u)) >> 16;
}

// ---------------- U transpose + hi/lo split + per-block swizzled image ----------------
__global__ __launch_bounds__(256) void transpose_split(
    const f32* __restrict__ Uf, const f32* __restrict__ Ub, u16* __restrict__ USW)
{
  __shared__ f32 tile[32][33];
  const int d = blockIdx.z;
  const f32* Uw = d ? Ub : Uf;
  const int c0 = blockIdx.x * 32;
  const int k0 = blockIdx.y * 32;
  const int tx = threadIdx.x & 31;
  const int ty = threadIdx.x >> 5;
#pragma unroll
  for (int i = 0; i < 4; i++) {
    int kl = ty + i * 8;
    tile[kl][tx] = Uw[(size_t)(k0 + kl) * G3 + c0 + tx];
  }
  __syncthreads();
#pragma unroll
  for (int i = 0; i < 4; i++) {
    int cl = ty + i * 8;
    int c  = c0 + cl;
    f32 val = tile[tx][cl];
    int g = c >> 10, u = c & 1023;
    int blk = d * 128 + (u >> 3);
    int r   = g * 8 + (u & 7);
    u32 hib = f32_to_bf16_rne(val);
    f32 rem = val - __uint_as_float(hib << 16);
    u32 lob = f32_to_bf16_rne(rem);
    int k = k0 + tx;
    int slot = (k >> 3) ^ (r & 7);
    size_t base = ((size_t)blk * 2) * (24 * 1024);
    size_t off  = (size_t)r * 1024 + slot * 8 + (k & 7);
    USW[base + off] = (u16)hib;
    USW[base + (size_t)24 * 1024 + off] = (u16)lob;
  }
}

// ---------------- input projection: XG[d][s][b][col] = emb[tok(d,s,b)] @ W_d + bi_d ----------------
__global__ __launch_bounds__(256) void xg_gemm(
    const int* __restrict__ tokens, const f32* __restrict__ emb,
    const f32* __restrict__ Wf, const f32* __restrict__ bif,
    const f32* __restrict__ Wb, const f32* __restrict__ bib,
    bf16* __restrict__ XG)
{
  __shared__ f32 As[8][128];
  __shared__ f32 Bs[8][128];
  __shared__ int tok_s[128];

  const int tid = threadIdx.x;
  const int n0 = blockIdx.x * 128;
  const int m0 = blockIdx.y * 128;
  const int dir = (m0 >= T_LEN * B_SZ) ? 1 : 0;
  const f32* W  = dir ? Wb : Wf;
  const f32* bi = dir ? bib : bif;

  if (tid < 128) {
    int mm = m0 + tid - dir * (T_LEN * B_SZ);
    int s = mm >> 6, b = mm & 63;
    int t_orig = dir ? s : (T_LEN - 1 - s);
    tok_s[tid] = tokens[b * T_LEN + t_orig];
  }
  __syncthreads();

  const int lr = tid >> 1;
  const int lh = (tid & 1) * 4;
  const int bk = tid >> 5;
  const int bn = (tid & 31) * 4;
  const f32* arow = emb + (size_t)tok_s[lr] * E_DIM + lh;
  const f32* brow = W + (size_t)bk * G3 + n0 + bn;

  const int tm = tid >> 4;
  const int tn = tid & 15;

  f32 acc[8][8];
#pragma unroll
  for (int i = 0; i < 8; i++)
#pragma unroll
    for (int j = 0; j < 8; j++) acc[i][j] = 0.f;

  for (int k0 = 0; k0 < E_DIM; k0 += 8) {
    float4 av = *(const float4*)(arow + k0);
    float4 bv = *(const float4*)(brow + (size_t)k0 * G3);
    __syncthreads();
    As[lh + 0][lr] = av.x;
    As[lh + 1][lr] = av.y;
    As[lh + 2][lr] = av.z;
    As[lh + 3][lr] = av.w;
    *(float4*)&Bs[bk][bn] = bv;
    __syncthreads();
#pragma unroll
    for (int kk = 0; kk < 8; kk++) {
      float4 a0 = *(float4*)&As[kk][tm * 4];
      float4 a1 = *(float4*)&As[kk][64 + tm * 4];
      float4 b0 = *(float4*)&Bs[kk][tn * 4];
      float4 b1 = *(float4*)&Bs[kk][64 + tn * 4];
      f32 am[8] = {a0.x,a0.y,a0.z,a0.w,a1.x,a1.y,a1.z,a1.w};
      f32 bb[8] = {b0.x,b0.y,b0.z,b0.w,b1.x,b1.y,b1.z,b1.w};
#pragma unroll
      for (int i = 0; i < 8; i++)
#pragma unroll
        for (int j = 0; j < 8; j++)
          acc[i][j] += am[i] * bb[j];
    }
  }

  f32 biv[8];
#pragma unroll
  for (int j = 0; j < 8; j++) {
    int nloc = tn * 4 + (j & 3) + (j >> 2) * 64;
    biv[j] = bi[n0 + nloc];
  }
#pragma unroll
  for (int i = 0; i < 8; i++) {
    int mloc = tm * 4 + (i & 3) + (i >> 2) * 64;
    int mm = m0 + mloc - dir * (T_LEN * B_SZ);
    int s = mm >> 6, b = mm & 63;
    size_t rowbase = ((size_t)(dir * T_LEN + s) * B_SZ + b) * G3;
#pragma unroll
    for (int j = 0; j < 8; j++) {
      int nloc = tn * 4 + (j & 3) + (j >> 2) * 64;
      XG[rowbase + n0 + nloc] = __float2bfloat16(acc[i][j] + biv[j]);
    }
  }
}

// ---------------- one recurrence step, launched 128x ----------------
// 256 blocks (dir x 128 u-slices of 8) x 1024 threads (16 waves: 4 b-tiles x 4 k-quarters).
// H in separate hi/lo u16 planes, [b][k] layout -> one dwordx4 per 8-k fragment, no unpack.
// 4-deep register prefetch of H batches to cover LLC latency.
__global__ __launch_bounds__(1024, 4) void gru_step3(
    const u16* __restrict__ USW,
    u16* __restrict__ Hq2,           // [2 buf][2 plane][2 dir][64 b][1024 k]
    const u16* __restrict__ XG,      // bf16 bits [2][128][64][3072]
    const f32* __restrict__ bhf, const f32* __restrict__ bhb,
    f32* __restrict__ out, int s)
{
  extern __shared__ u16 Us[];        // 96 KB U image + 24 KB reduce
  const int blk = blockIdx.x;
  const int dir = blk >> 7;
  const int su  = (blk & 127) * 8;
  const int tid = threadIdx.x;
  const int lane = tid & 63;
  const int w  = tid >> 6;
  const int nw = w & 3, kw = w >> 2;   // b-tile, k-quarter

  // stage per-block U image (swizzle baked into global layout)
  {
    const us8* src = (const us8*)(USW + (size_t)blk * (2 * 24 * 1024));
    us8* dst = (us8*)Us;
#pragma unroll
    for (int i = 0; i < 6; i++) dst[tid + i * 1024] = src[tid + i * 1024];
  }

  const int bb = nw * 16 + (lane & 15);
  const int ko = (lane >> 4) * 8;
  const int kq = kw * 256;
  const int r0 = lane & 15;
  const int r1t = 16 + (lane & 15);
  const int r1 = r1t > 23 ? 23 : r1t;   // clamped rows produce garbage only in unread output rows

  const int rb_h0 = (0 * 24 + r0) * 2048;
  const int rb_l0 = (1 * 24 + r0) * 2048;
  const int rb_h1 = (0 * 24 + r1) * 2048;
  const int rb_l1 = (1 * 24 + r1) * 2048;
  const int sw0 = r0 & 7, sw1 = r1 & 7;

  const int bufr = s & 1, bufw = bufr ^ 1;
  const u16* HrHi = Hq2 + (size_t)(((bufr * 2 + 0) * 2 + dir) * 64 + bb) * 1024;
  const u16* HrLo = Hq2 + (size_t)(((bufr * 2 + 1) * 2 + dir) * 64 + bb) * 1024;

  // prologue: 4-deep H prefetch (batches ks=0..3), issued before the barrier
  F8 h_hi0, h_lo0, h_hi1, h_lo1, h_hi2, h_lo2, h_hi3, h_lo3;
  if (s) {
    const u16* p = HrHi + kq + ko;
    const u16* q = HrLo + kq + ko;
    h_hi0.u = *(const us8*)(p);        h_lo0.u = *(const us8*)(q);
    h_hi1.u = *(const us8*)(p + 32);   h_lo1.u = *(const us8*)(q + 32);
    h_hi2.u = *(const us8*)(p + 64);   h_lo2.u = *(const us8*)(q + 64);
    h_hi3.u = *(const us8*)(p + 96);   h_lo3.u = *(const us8*)(q + 96);
  }

  __syncthreads();

  f32x4 acc0 = {0.f, 0.f, 0.f, 0.f};
  f32x4 acc1 = {0.f, 0.f, 0.f, 0.f};

#define DOMFMA(HHI, HLO, KS) { \
    const int slot = (kq >> 3) + (KS) * 4 + (lane >> 4); \
    F8 ah0, al0, ah1, al1; \
    ah0.u = *(const us8*)((const char*)Us + rb_h0 + ((slot ^ sw0) << 4)); \
    al0.u = *(const us8*)((const char*)Us + rb_l0 + ((slot ^ sw0) << 4)); \
    ah1.u = *(const us8*)((const char*)Us + rb_h1 + ((slot ^ sw1) << 4)); \
    al1.u = *(const us8*)((const char*)Us + rb_l1 + ((slot ^ sw1) << 4)); \
    acc0 = __builtin_amdgcn_mfma_f32_16x16x32_bf16(ah0.b, HHI.b, acc0, 0, 0, 0); \
    acc0 = __builtin_amdgcn_mfma_f32_16x16x32_bf16(ah0.b, HLO.b, acc0, 0, 0, 0); \
    acc0 = __builtin_amdgcn_mfma_f32_16x16x32_bf16(al0.b, HHI.b, acc0, 0, 0, 0); \
    acc1 = __builtin_amdgcn_mfma_f32_16x16x32_bf16(ah1.b, HHI.b, acc1, 0, 0, 0); \
    acc1 = __builtin_amdgcn_mfma_f32_16x16x32_bf16(ah1.b, HLO.b, acc1, 0, 0, 0); \
    acc1 = __builtin_amdgcn_mfma_f32_16x16x32_bf16(al1.b, HHI.b, acc1, 0, 0, 0); \
  }
#define LDH(HHI, HLO, KS) { \
    HHI.u = *(const us8*)(HrHi + kq + ko + (KS) * 32); \
    HLO.u = *(const us8*)(HrLo + kq + ko + (KS) * 32); \
  }

  if (s) {
    DOMFMA(h_hi0, h_lo0, 0) LDH(h_hi0, h_lo0, 4)
    DOMFMA(h_hi1, h_lo1, 1) LDH(h_hi1, h_lo1, 5)
    DOMFMA(h_hi2, h_lo2, 2) LDH(h_hi2, h_lo2, 6)
    DOMFMA(h_hi3, h_lo3, 3) LDH(h_hi3, h_lo3, 7)
    DOMFMA(h_hi0, h_lo0, 4)
    DOMFMA(h_hi1, h_lo1, 5)
    DOMFMA(h_hi2, h_lo2, 6)
    DOMFMA(h_hi3, h_lo3, 7)
  }
#undef DOMFMA
#undef LDH

  // k-quarter reduction through LDS
  __syncthreads();
  f32* red = (f32*)(Us + 49152);     // [3][4][64][8] f32 = 24 KB
  if (kw) {
    f32* p = red + (size_t)(((kw - 1) * 4 + nw) * 64 + lane) * 8;
    *(f32x4*)p = acc0;
    *(f32x4*)(p + 4) = acc1;
  }
  __syncthreads();
  if (kw == 0) {
#pragma unroll
    for (int g = 0; g < 3; g++) {
      const f32* p = red + (size_t)((g * 4 + nw) * 64 + lane) * 8;
      f32x4 o0 = *(const f32x4*)p;
      f32x4 o1 = *(const f32x4*)(p + 4);
#pragma unroll
      for (int i = 0; i < 4; i++) { acc0[i] += o0[i]; acc1[i] += o1[i]; }
    }

    f32 racc[4];
#pragma unroll
    for (int j = 0; j < 4; j++) racc[j] = __shfl_xor(acc0[j], 32);   // r-gate rows (8..15)

    if (lane < 32) {
      const int ul0 = (lane >> 4) * 4;     // 0 or 4
      const int u0 = su + ul0;
      const u16* xgp = XG + ((size_t)(dir * T_LEN + s) * B_SZ + bb) * G3;
      us4 gz = *(const us4*)(xgp + u0);
      us4 gr = *(const us4*)(xgp + 1024 + u0);
      us4 gh = *(const us4*)(xgp + 2048 + u0);
      us4 ohi = {0, 0, 0, 0}, olo = {0, 0, 0, 0};
      if (s) {
        ohi = *(const us4*)(HrHi + u0);    // HrHi already includes bb*1024
        olo = *(const us4*)(HrLo + u0);
      }
      const f32* bh = dir ? bhb : bhf;
      f32x4 hnv;
      us4 whi, wlo;
#pragma unroll
      for (int j = 0; j < 4; j++) {
        const int u = u0 + j;
        f32 hz = acc0[j] + bh[u];
        f32 hr = racc[j] + bh[1024 + u];
        f32 hh = acc1[j] + bh[2048 + u];
        f32 xz = __uint_as_float((u32)gz[j] << 16);
        f32 xr = __uint_as_float((u32)gr[j] << 16);
        f32 xh = __uint_as_float((u32)gh[j] << 16);
        f32 hold = __uint_as_float((u32)ohi[j] << 16) + __uint_as_float((u32)olo[j] << 16);

        f32 z  = 1.f / (1.f + expf(-(xz + hz)));
        f32 r  = 1.f / (1.f + expf(-(xr + hr)));
        f32 hc = tanhf(xh + r * hh);
        f32 hnew = z * hold + (1.f - z) * hc;

        u32 hib = f32_to_bf16_rne(hnew);
        f32 rem = hnew - __uint_as_float(hib << 16);
        u32 lob = f32_to_bf16_rne(rem);
        hnv[j] = hnew;
        whi[j] = (u16)hib;
        wlo[j] = (u16)lob;
      }
      u16* HwHi = Hq2 + (size_t)(((bufw * 2 + 0) * 2 + dir) * 64 + bb) * 1024;
      u16* HwLo = Hq2 + (size_t)(((bufw * 2 + 1) * 2 + dir) * 64 + bb) * 1024;
      *(us4*)(HwHi + u0) = whi;
      *(us4*)(HwLo + u0) = wlo;

      const int t = dir ? (T_LEN - 1 - s) : s;
      f32* op = out + ((size_t)bb * T_LEN + t) * U_DIM + u0;
      if (s < 64) {
        *(f32x4*)op = hnv;
      } else {
        f32x4 prev = *(const f32x4*)op;
#pragma unroll
        for (int j = 0; j < 4; j++) prev[j] += hnv[j];
        *(f32x4*)op = prev;
      }
      if (s == T_LEN - 1)
        *(f32x4*)(out + (size_t)BTU + (size_t)bb * 2048 + dir * 1024 + u0) = hnv;
    }
  }
}

extern "C" void kernel_launch(void* const* d_in, const int* in_sizes, int n_in,
                              void* d_out, int out_size, void* d_ws, size_t ws_size,
                              hipStream_t stream) {
  (void)in_sizes; (void)n_in; (void)out_size; (void)ws_size;
  const int* tokens = (const int*)d_in[0];
  const f32* emb = (const f32*)d_in[1];
  const f32* Wf  = (const f32*)d_in[2];
  const f32* Uf  = (const f32*)d_in[3];
  const f32* bif = (const f32*)d_in[4];
  const f32* bhf = (const f32*)d_in[5];
  const f32* Wb  = (const f32*)d_in[6];
  const f32* Ub  = (const f32*)d_in[7];
  const f32* bib = (const f32*)d_in[8];
  const f32* bhb = (const f32*)d_in[9];

  char* ws = (char*)d_ws;
  u16*  USW = (u16*)(ws + WS_USW);
  u16*  Hq2 = (u16*)(ws + WS_HQ);
  bf16* XG  = (bf16*)(ws + WS_XG);
  f32*  out = (f32*)d_out;

  transpose_split<<<dim3(96, 32, 2), 256, 0, stream>>>(Uf, Ub, USW);
  xg_gemm<<<dim3(24, 128), 256, 0, stream>>>(tokens, emb, Wf, bif, Wb, bib, XG);

  hipFuncSetAttribute((const void*)gru_step3,
                      hipFuncAttributeMaxDynamicSharedMemorySize, LDS_BYTES);
  for (int s = 0; s < T_LEN; s++)
    gru_step3<<<256, 1024, LDS_BYTES, stream>>>(USW, Hq2, (const u16*)XG, bhf, bhb, out, s);
}

// Round 6
// 2259.593 us; speedup vs baseline: 2.0598x; 1.1429x over previous
//
#include <hip/hip_runtime.h>
#include <hip/hip_bf16.h>

typedef float f32;
typedef __hip_bfloat16 bf16;
typedef unsigned int u32;
typedef unsigned short u16;

#define T_LEN 128
#define B_SZ  64
#define E_DIM 512
#define U_DIM 1024
#define G3    3072
#define BTU   (B_SZ * T_LEN * U_DIM)

typedef __attribute__((ext_vector_type(8))) __bf16 bf16x8;
typedef __attribute__((ext_vector_type(8))) u16  us8;
typedef __attribute__((ext_vector_type(4))) u16  us4;
typedef __attribute__((ext_vector_type(4))) f32  f32x4;

union F8 { us8 u; bf16x8 b; };

// workspace layout (bytes)
#define WS_USW 0u            // bf16 bits [256 blk][2 plane][24 row][1024 k] swizzled = 25165824 B
#define WS_HQ  25165824u     // u16 [2 buf][2 plane][2 dir][64 b][1024 k] = 524288 B
#define WS_XG  26214400u     // bf16 [2][128][64 b][3072 col] = 100663296 B

#define STEP_LDS 106496      // 96 KB U image + 8 KB reduce
#define XG_LDS   66048       // 2x32KB A/B hi-lo tiles + tok_s

__device__ __forceinline__ u32 f32_to_bf16_rne(f32 x) {
  u32 b = __float_as_uint(x);
  return (b + 0x7fffu + ((b >> 16) & 1u)) >> 16;
}

// ---------------- U transpose + hi/lo split + per-block swizzled image ----------------
__global__ __launch_bounds__(256) void transpose_split(
    const f32* __restrict__ Uf, const f32* __restrict__ Ub, u16* __restrict__ USW)
{
  __shared__ f32 tile[32][33];
  const int d = blockIdx.z;
  const f32* Uw = d ? Ub : Uf;
  const int c0 = blockIdx.x * 32;
  const int k0 = blockIdx.y * 32;
  const int tx = threadIdx.x & 31;
  const int ty = threadIdx.x >> 5;
#pragma unroll
  for (int i = 0; i < 4; i++) {
    int kl = ty + i * 8;
    tile[kl][tx] = Uw[(size_t)(k0 + kl) * G3 + c0 + tx];
  }
  __syncthreads();
#pragma unroll
  for (int i = 0; i < 4; i++) {
    int cl = ty + i * 8;
    int c  = c0 + cl;
    f32 val = tile[tx][cl];
    int g = c >> 10, u = c & 1023;
    int blk = d * 128 + (u >> 3);
    int r   = g * 8 + (u & 7);
    u32 hib = f32_to_bf16_rne(val);
    f32 rem = val - __uint_as_float(hib << 16);
    u32 lob = f32_to_bf16_rne(rem);
    int k = k0 + tx;
    int slot = (k >> 3) ^ (r & 7);
    size_t base = ((size_t)blk * 2) * (24 * 1024);
    size_t off  = (size_t)r * 1024 + slot * 8 + (k & 7);
    USW[base + off] = (u16)hib;
    USW[base + (size_t)24 * 1024 + off] = (u16)lob;
  }
}

// ---------------- input projection, MFMA hi/lo: XG[d][s][b][col] ----------------
// grid (24 nblk, 128 mblk), 256 thr = 4 waves. Tile 128m x 128n, K-step 64.
// A = gathered emb rows (hi/lo bf16), B = W cols (hi/lo bf16), 3-MFMA product.
__global__ __launch_bounds__(256) void xg_gemm_mfma(
    const int* __restrict__ tokens, const f32* __restrict__ emb,
    const f32* __restrict__ Wf, const f32* __restrict__ bif,
    const f32* __restrict__ Wb, const f32* __restrict__ bib,
    bf16* __restrict__ XG)
{
  extern __shared__ u16 XL[];        // Ash[2][128][64] | Bsh[2][128][64] | tok_s[128]
  u16* Ash = XL;                     // (plane*128 + row)*64 + k, slot-swizzled
  u16* Bsh = XL + 16384;
  int* tok_s = (int*)(XL + 32768);

  const int tid = threadIdx.x;
  const int n0 = blockIdx.x * 128;
  const int by = blockIdx.y;
  const int dir = by >> 6;
  const int s0 = (by & 63) * 2;
  const f32* W  = dir ? Wb : Wf;
  const f32* bi = dir ? bib : bif;

  if (tid < 128) {
    int srow = s0 + (tid >> 6);
    int b = tid & 63;
    int t_orig = dir ? srow : (T_LEN - 1 - srow);
    tok_s[tid] = tokens[b * T_LEN + t_orig];
  }
  __syncthreads();

  const int wv = tid >> 6;
  const int lane = tid & 63;
  const int arow = tid >> 1;           // 0..127
  const int akoff = (tid & 1) * 32;    // 0/32
  const int bcol = tid & 127;
  const int bkoff = (tid >> 7) * 32;

  f32x4 acc[2][8];
#pragma unroll
  for (int mi = 0; mi < 2; mi++)
#pragma unroll
    for (int ni = 0; ni < 8; ni++) acc[mi][ni] = (f32x4){0.f, 0.f, 0.f, 0.f};

  const f32* asrc0 = emb + (size_t)tok_s[arow] * E_DIM + akoff;

  for (int kk = 0; kk < 8; kk++) {
    __syncthreads();
    // ---- stage A (emb gather, f32 -> hi/lo bf16) ----
    {
      const f32* src = asrc0 + kk * 64;
#pragma unroll
      for (int g = 0; g < 4; g++) {
        float4 v0 = *(const float4*)(src + g * 8);
        float4 v1 = *(const float4*)(src + g * 8 + 4);
        f32 vv[8] = {v0.x,v0.y,v0.z,v0.w,v1.x,v1.y,v1.z,v1.w};
        us8 h8, l8;
#pragma unroll
        for (int e = 0; e < 8; e++) {
          u32 bb = __float_as_uint(vv[e]);
          h8[e] = (u16)(bb >> 16);
          f32 rem = vv[e] - __uint_as_float(bb & 0xffff0000u);
          l8[e] = (u16)f32_to_bf16_rne(rem);
        }
        int sl = (((akoff >> 3) + g) ^ (arow & 7)) * 8;
        *(us8*)&Ash[(size_t)arow * 64 + sl] = h8;
        *(us8*)&Ash[(size_t)(128 + arow) * 64 + sl] = l8;
      }
    }
    // ---- stage B (W columns, f32 -> hi/lo bf16, transpose to [n][k]) ----
    {
      const f32* src = W + (size_t)(kk * 64 + bkoff) * G3 + n0 + bcol;
#pragma unroll
      for (int g = 0; g < 4; g++) {
        us8 h8, l8;
#pragma unroll
        for (int e = 0; e < 8; e++) {
          f32 v = src[(size_t)(g * 8 + e) * G3];
          u32 bb = __float_as_uint(v);
          h8[e] = (u16)(bb >> 16);
          f32 rem = v - __uint_as_float(bb & 0xffff0000u);
          l8[e] = (u16)f32_to_bf16_rne(rem);
        }
        int sl = (((bkoff >> 3) + g) ^ (bcol & 7)) * 8;
        *(us8*)&Bsh[(size_t)bcol * 64 + sl] = h8;
        *(us8*)&Bsh[(size_t)(128 + bcol) * 64 + sl] = l8;
      }
    }
    __syncthreads();
    // ---- compute: 2 k-subtiles of 32 ----
#pragma unroll
    for (int ks = 0; ks < 2; ks++) {
      F8 ah[2], al[2];
#pragma unroll
      for (int mi = 0; mi < 2; mi++) {
        int row = wv * 32 + mi * 16 + (lane & 15);
        int sl = ((ks * 4 + (lane >> 4)) ^ (row & 7)) * 8;
        ah[mi].u = *(const us8*)&Ash[(size_t)row * 64 + sl];
        al[mi].u = *(const us8*)&Ash[(size_t)(128 + row) * 64 + sl];
      }
#pragma unroll
      for (int ni = 0; ni < 8; ni++) {
        int col = ni * 16 + (lane & 15);
        int sl = ((ks * 4 + (lane >> 4)) ^ (col & 7)) * 8;
        F8 bh, bl;
        bh.u = *(const us8*)&Bsh[(size_t)col * 64 + sl];
        bl.u = *(const us8*)&Bsh[(size_t)(128 + col) * 64 + sl];
#pragma unroll
        for (int mi = 0; mi < 2; mi++) {
          acc[mi][ni] = __builtin_amdgcn_mfma_f32_16x16x32_bf16(ah[mi].b, bh.b, acc[mi][ni], 0, 0, 0);
          acc[mi][ni] = __builtin_amdgcn_mfma_f32_16x16x32_bf16(ah[mi].b, bl.b, acc[mi][ni], 0, 0, 0);
          acc[mi][ni] = __builtin_amdgcn_mfma_f32_16x16x32_bf16(al[mi].b, bh.b, acc[mi][ni], 0, 0, 0);
        }
      }
    }
  }
  // ---- epilogue: + bias, store bf16 to XG[d][s][b][col] ----
#pragma unroll
  for (int ni = 0; ni < 8; ni++) {
    int ncol = n0 + ni * 16 + (lane & 15);
    f32 bv = bi[ncol];
#pragma unroll
    for (int mi = 0; mi < 2; mi++) {
#pragma unroll
      for (int j = 0; j < 4; j++) {
        int row = wv * 32 + mi * 16 + (lane >> 4) * 4 + j;
        int srow = s0 + (row >> 6);
        int b = row & 63;
        XG[((size_t)(dir * T_LEN + srow) * B_SZ + b) * G3 + ncol] =
            __float2bfloat16(acc[mi][ni][j] + bv);
      }
    }
  }
}

// ---------------- one recurrence step, launched 128x ----------------
// 256 blocks (dir x 128 u-slices of 8) x 512 threads (8 waves: 4 b-tiles x 2 k-halves).
// H in hi/lo u16 planes [b][k]; 4-deep register prefetch of H; U image in LDS.
__global__ __launch_bounds__(512) void gru_step4(
    const u16* __restrict__ USW,
    u16* __restrict__ Hq2,           // [2 buf][2 plane][2 dir][64 b][1024 k]
    const u16* __restrict__ XG,      // bf16 bits [2][128][64][3072]
    const f32* __restrict__ bhf, const f32* __restrict__ bhb,
    f32* __restrict__ out, int s)
{
  extern __shared__ u16 Us[];        // 96 KB U image + 8 KB reduce
  const int blk = blockIdx.x;
  const int dir = blk >> 7;
  const int su  = (blk & 127) * 8;
  const int tid = threadIdx.x;
  const int lane = tid & 63;
  const int w  = tid >> 6;
  const int nw = w & 3, kw = w >> 2;   // b-tile, k-half

  const int bb = nw * 16 + (lane & 15);
  const int ko = (lane >> 4) * 8;
  const int kq = kw * 512;
  const int r0 = lane & 15;
  const int r1t = 16 + (lane & 15);
  const int r1 = r1t > 23 ? 23 : r1t;

  const int rb_h0 = (0 * 24 + r0) * 2048;
  const int rb_l0 = (1 * 24 + r0) * 2048;
  const int rb_h1 = (0 * 24 + r1) * 2048;
  const int rb_l1 = (1 * 24 + r1) * 2048;
  const int sw0 = r0 & 7, sw1 = r1 & 7;

  const int bufr = s & 1, bufw = bufr ^ 1;
  const u16* HrHi = Hq2 + (size_t)(((bufr * 2 + 0) * 2 + dir) * 64 + bb) * 1024;
  const u16* HrLo = Hq2 + (size_t)(((bufr * 2 + 1) * 2 + dir) * 64 + bb) * 1024;

  // prologue: 4-deep H prefetch, issued BEFORE staging so it overlaps
  F8 h_hi0, h_lo0, h_hi1, h_lo1, h_hi2, h_lo2, h_hi3, h_lo3;
  if (s) {
    const u16* p = HrHi + kq + ko;
    const u16* q = HrLo + kq + ko;
    h_hi0.u = *(const us8*)(p);        h_lo0.u = *(const us8*)(q);
    h_hi1.u = *(const us8*)(p + 32);   h_lo1.u = *(const us8*)(q + 32);
    h_hi2.u = *(const us8*)(p + 64);   h_lo2.u = *(const us8*)(q + 64);
    h_hi3.u = *(const us8*)(p + 96);   h_lo3.u = *(const us8*)(q + 96);
  }

  // stage per-block U image (swizzle baked into global layout)
  {
    const us8* src = (const us8*)(USW + (size_t)blk * (2 * 24 * 1024));
    us8* dst = (us8*)Us;
#pragma unroll
    for (int i = 0; i < 12; i++) dst[tid + i * 512] = src[tid + i * 512];
  }

  __syncthreads();

  f32x4 acc0 = {0.f, 0.f, 0.f, 0.f};
  f32x4 acc1 = {0.f, 0.f, 0.f, 0.f};

#define DOMFMA(HHI, HLO, KS) { \
    const int slot = (kq >> 3) + (KS) * 4 + (lane >> 4); \
    F8 ah0, al0, ah1, al1; \
    ah0.u = *(const us8*)((const char*)Us + rb_h0 + ((slot ^ sw0) << 4)); \
    al0.u = *(const us8*)((const char*)Us + rb_l0 + ((slot ^ sw0) << 4)); \
    ah1.u = *(const us8*)((const char*)Us + rb_h1 + ((slot ^ sw1) << 4)); \
    al1.u = *(const us8*)((const char*)Us + rb_l1 + ((slot ^ sw1) << 4)); \
    acc0 = __builtin_amdgcn_mfma_f32_16x16x32_bf16(ah0.b, HHI.b, acc0, 0, 0, 0); \
    acc0 = __builtin_amdgcn_mfma_f32_16x16x32_bf16(ah0.b, HLO.b, acc0, 0, 0, 0); \
    acc0 = __builtin_amdgcn_mfma_f32_16x16x32_bf16(al0.b, HHI.b, acc0, 0, 0, 0); \
    acc1 = __builtin_amdgcn_mfma_f32_16x16x32_bf16(ah1.b, HHI.b, acc1, 0, 0, 0); \
    acc1 = __builtin_amdgcn_mfma_f32_16x16x32_bf16(ah1.b, HLO.b, acc1, 0, 0, 0); \
    acc1 = __builtin_amdgcn_mfma_f32_16x16x32_bf16(al1.b, HHI.b, acc1, 0, 0, 0); \
  }
#define LDH(HHI, HLO, KS) { \
    HHI.u = *(const us8*)(HrHi + kq + ko + (KS) * 32); \
    HLO.u = *(const us8*)(HrLo + kq + ko + (KS) * 32); \
  }

  if (s) {
    DOMFMA(h_hi0, h_lo0, 0)  LDH(h_hi0, h_lo0, 4)
    DOMFMA(h_hi1, h_lo1, 1)  LDH(h_hi1, h_lo1, 5)
    DOMFMA(h_hi2, h_lo2, 2)  LDH(h_hi2, h_lo2, 6)
    DOMFMA(h_hi3, h_lo3, 3)  LDH(h_hi3, h_lo3, 7)
    DOMFMA(h_hi0, h_lo0, 4)  LDH(h_hi0, h_lo0, 8)
    DOMFMA(h_hi1, h_lo1, 5)  LDH(h_hi1, h_lo1, 9)
    DOMFMA(h_hi2, h_lo2, 6)  LDH(h_hi2, h_lo2, 10)
    DOMFMA(h_hi3, h_lo3, 7)  LDH(h_hi3, h_lo3, 11)
    DOMFMA(h_hi0, h_lo0, 8)  LDH(h_hi0, h_lo0, 12)
    DOMFMA(h_hi1, h_lo1, 9)  LDH(h_hi1, h_lo1, 13)
    DOMFMA(h_hi2, h_lo2, 10) LDH(h_hi2, h_lo2, 14)
    DOMFMA(h_hi3, h_lo3, 11) LDH(h_hi3, h_lo3, 15)
    DOMFMA(h_hi0, h_lo0, 12)
    DOMFMA(h_hi1, h_lo1, 13)
    DOMFMA(h_hi2, h_lo2, 14)
    DOMFMA(h_hi3, h_lo3, 15)
  }
#undef DOMFMA
#undef LDH

  // k-half reduction through LDS
  __syncthreads();
  f32* red = (f32*)(Us + 49152);     // [4][64][8] f32 = 8 KB
  if (kw == 1) {
    f32* p = red + (size_t)(nw * 64 + lane) * 8;
    *(f32x4*)p = acc0;
    *(f32x4*)(p + 4) = acc1;
  }
  __syncthreads();
  if (kw == 0) {
    const f32* p = red + (size_t)(nw * 64 + lane) * 8;
    f32x4 o0 = *(const f32x4*)p;
    f32x4 o1 = *(const f32x4*)(p + 4);
#pragma unroll
    for (int i = 0; i < 4; i++) { acc0[i] += o0[i]; acc1[i] += o1[i]; }

    f32 racc[4];
#pragma unroll
    for (int j = 0; j < 4; j++) racc[j] = __shfl_xor(acc0[j], 32);   // r-gate rows (8..15)

    if (lane < 32) {
      const int ul0 = (lane >> 4) * 4;     // 0 or 4
      const int u0 = su + ul0;
      const u16* xgp = XG + ((size_t)(dir * T_LEN + s) * B_SZ + bb) * G3;
      us4 gz = *(const us4*)(xgp + u0 - su + su);     // cols su..; col index = u0
      gz = *(const us4*)(xgp + u0);
      us4 gr = *(const us4*)(xgp + 1024 + u0);
      us4 gh = *(const us4*)(xgp + 2048 + u0);
      us4 ohi = {0, 0, 0, 0}, olo = {0, 0, 0, 0};
      if (s) {
        ohi = *(const us4*)(HrHi + u0);
        olo = *(const us4*)(HrLo + u0);
      }
      const f32* bh = dir ? bhb : bhf;
      f32x4 hnv;
      us4 whi, wlo;
#pragma unroll
      for (int j = 0; j < 4; j++) {
        const int u = u0 + j;
        f32 hz = acc0[j] + bh[u];
        f32 hr = racc[j] + bh[1024 + u];
        f32 hh = acc1[j] + bh[2048 + u];
        f32 xz = __uint_as_float((u32)gz[j] << 16);
        f32 xr = __uint_as_float((u32)gr[j] << 16);
        f32 xh = __uint_as_float((u32)gh[j] << 16);
        f32 hold = __uint_as_float((u32)ohi[j] << 16) + __uint_as_float((u32)olo[j] << 16);

        f32 z  = 1.f / (1.f + expf(-(xz + hz)));
        f32 r  = 1.f / (1.f + expf(-(xr + hr)));
        f32 hc = tanhf(xh + r * hh);
        f32 hnew = z * hold + (1.f - z) * hc;

        u32 hib = f32_to_bf16_rne(hnew);
        f32 rem = hnew - __uint_as_float(hib << 16);
        u32 lob = f32_to_bf16_rne(rem);
        hnv[j] = hnew;
        whi[j] = (u16)hib;
        wlo[j] = (u16)lob;
      }
      u16* HwHi = Hq2 + (size_t)(((bufw * 2 + 0) * 2 + dir) * 64 + bb) * 1024;
      u16* HwLo = Hq2 + (size_t)(((bufw * 2 + 1) * 2 + dir) * 64 + bb) * 1024;
      *(us4*)(HwHi + u0) = whi;
      *(us4*)(HwLo + u0) = wlo;

      const int t = dir ? (T_LEN - 1 - s) : s;
      f32* op = out + ((size_t)bb * T_LEN + t) * U_DIM + u0;
      if (s < 64) {
        *(f32x4*)op = hnv;
      } else {
        f32x4 prev = *(const f32x4*)op;
#pragma unroll
        for (int j = 0; j < 4; j++) prev[j] += hnv[j];
        *(f32x4*)op = prev;
      }
      if (s == T_LEN - 1)
        *(f32x4*)(out + (size_t)BTU + (size_t)bb * 2048 + dir * 1024 + u0) = hnv;
    }
  }
}

extern "C" void kernel_launch(void* const* d_in, const int* in_sizes, int n_in,
                              void* d_out, int out_size, void* d_ws, size_t ws_size,
                              hipStream_t stream) {
  (void)in_sizes; (void)n_in; (void)out_size; (void)ws_size;
  const int* tokens = (const int*)d_in[0];
  const f32* emb = (const f32*)d_in[1];
  const f32* Wf  = (const f32*)d_in[2];
  const f32* Uf  = (const f32*)d_in[3];
  const f32* bif = (const f32*)d_in[4];
  const f32* bhf = (const f32*)d_in[5];
  const f32* Wb  = (const f32*)d_in[6];
  const f32* Ub  = (const f32*)d_in[7];
  const f32* bib = (const f32*)d_in[8];
  const f32* bhb = (const f32*)d_in[9];

  char* ws = (char*)d_ws;
  u16*  USW = (u16*)(ws + WS_USW);
  u16*  Hq2 = (u16*)(ws + WS_HQ);
  bf16* XG  = (bf16*)(ws + WS_XG);
  f32*  out = (f32*)d_out;

  transpose_split<<<dim3(96, 32, 2), 256, 0, stream>>>(Uf, Ub, USW);

  hipFuncSetAttribute((const void*)xg_gemm_mfma,
                      hipFuncAttributeMaxDynamicSharedMemorySize, XG_LDS);
  xg_gemm_mfma<<<dim3(24, 128), 256, XG_LDS, stream>>>(tokens, emb, Wf, bif, Wb, bib, XG);

  hipFuncSetAttribute((const void*)gru_step4,
                      hipFuncAttributeMaxDynamicSharedMemorySize, STEP_LDS);
  for (int s = 0; s < T_LEN; s++)
    gru_step4<<<256, 512, STEP_LDS, stream>>>(USW, Hq2, (const u16*)XG, bhf, bhb, out, s);
}

// Round 7
// 1892.406 us; speedup vs baseline: 2.4595x; 1.1940x over previous
//
#include <hip/hip_runtime.h>
#include <hip/hip_bf16.h>

typedef float f32;
typedef __hip_bfloat16 bf16;
typedef unsigned int u32;
typedef unsigned short u16;

#define T_LEN 128
#define B_SZ  64
#define E_DIM 512
#define U_DIM 1024
#define G3    3072
#define BTU   (B_SZ * T_LEN * U_DIM)

typedef __attribute__((ext_vector_type(8))) __bf16 bf16x8;
typedef __attribute__((ext_vector_type(8))) u16  us8;
typedef __attribute__((ext_vector_type(4))) u16  us4;
typedef __attribute__((ext_vector_type(4))) f32  f32x4;

union F8 { us8 u; bf16x8 b; };

// workspace layout (bytes)
#define WS_USW 0u            // bf16 bits [256 blk][2 plane][24 row][1024 k] swizzled = 25165824 B
#define WS_HQ  25165824u     // u32 [2 buf][2 dir][1024 k][64 b] packed (hi | lo<<16) = 1048576 B
#define WS_XG  26214400u     // bf16 [2][128][64 b][3072 col] = 100663296 B

#define STEP_LDS 98304       // 96 KB U image; reduce region aliases it (round-2 structure)
#define XG_LDS   66048       // 2x32KB A/B hi-lo tiles + tok_s

__device__ __forceinline__ u32 f32_to_bf16_rne(f32 x) {
  u32 b = __float_as_uint(x);
  return (b + 0x7fffu + ((b >> 16) & 1u)) >> 16;
}

// ---------------- U transpose + hi/lo split + per-block swizzled image ----------------
__global__ __launch_bounds__(256) void transpose_split(
    const f32* __restrict__ Uf, const f32* __restrict__ Ub, u16* __restrict__ USW)
{
  __shared__ f32 tile[32][33];
  const int d = blockIdx.z;
  const f32* Uw = d ? Ub : Uf;
  const int c0 = blockIdx.x * 32;
  const int k0 = blockIdx.y * 32;
  const int tx = threadIdx.x & 31;
  const int ty = threadIdx.x >> 5;
#pragma unroll
  for (int i = 0; i < 4; i++) {
    int kl = ty + i * 8;
    tile[kl][tx] = Uw[(size_t)(k0 + kl) * G3 + c0 + tx];
  }
  __syncthreads();
#pragma unroll
  for (int i = 0; i < 4; i++) {
    int cl = ty + i * 8;
    int c  = c0 + cl;
    f32 val = tile[tx][cl];
    int g = c >> 10, u = c & 1023;
    int blk = d * 128 + (u >> 3);
    int r   = g * 8 + (u & 7);
    u32 hib = f32_to_bf16_rne(val);
    f32 rem = val - __uint_as_float(hib << 16);
    u32 lob = f32_to_bf16_rne(rem);
    int k = k0 + tx;
    int slot = (k >> 3) ^ (r & 7);
    size_t base = ((size_t)blk * 2) * (24 * 1024);
    size_t off  = (size_t)r * 1024 + slot * 8 + (k & 7);
    USW[base + off] = (u16)hib;
    USW[base + (size_t)24 * 1024 + off] = (u16)lob;
  }
}

// ---------------- input projection, MFMA hi/lo (unchanged): XG[d][s][b][col] ----------------
__global__ __launch_bounds__(256) void xg_gemm_mfma(
    const int* __restrict__ tokens, const f32* __restrict__ emb,
    const f32* __restrict__ Wf, const f32* __restrict__ bif,
    const f32* __restrict__ Wb, const f32* __restrict__ bib,
    bf16* __restrict__ XG)
{
  extern __shared__ u16 XL[];        // Ash[2][128][64] | Bsh[2][128][64] | tok_s[128]
  u16* Ash = XL;
  u16* Bsh = XL + 16384;
  int* tok_s = (int*)(XL + 32768);

  const int tid = threadIdx.x;
  const int n0 = blockIdx.x * 128;
  const int by = blockIdx.y;
  const int dir = by >> 6;
  const int s0 = (by & 63) * 2;
  const f32* W  = dir ? Wb : Wf;
  const f32* bi = dir ? bib : bif;

  if (tid < 128) {
    int srow = s0 + (tid >> 6);
    int b = tid & 63;
    int t_orig = dir ? srow : (T_LEN - 1 - srow);
    tok_s[tid] = tokens[b * T_LEN + t_orig];
  }
  __syncthreads();

  const int wv = tid >> 6;
  const int lane = tid & 63;
  const int arow = tid >> 1;
  const int akoff = (tid & 1) * 32;
  const int bcol = tid & 127;
  const int bkoff = (tid >> 7) * 32;

  f32x4 acc[2][8];
#pragma unroll
  for (int mi = 0; mi < 2; mi++)
#pragma unroll
    for (int ni = 0; ni < 8; ni++) acc[mi][ni] = (f32x4){0.f, 0.f, 0.f, 0.f};

  const f32* asrc0 = emb + (size_t)tok_s[arow] * E_DIM + akoff;

  for (int kk = 0; kk < 8; kk++) {
    __syncthreads();
    {
      const f32* src = asrc0 + kk * 64;
#pragma unroll
      for (int g = 0; g < 4; g++) {
        float4 v0 = *(const float4*)(src + g * 8);
        float4 v1 = *(const float4*)(src + g * 8 + 4);
        f32 vv[8] = {v0.x,v0.y,v0.z,v0.w,v1.x,v1.y,v1.z,v1.w};
        us8 h8, l8;
#pragma unroll
        for (int e = 0; e < 8; e++) {
          u32 bb = __float_as_uint(vv[e]);
          h8[e] = (u16)(bb >> 16);
          f32 rem = vv[e] - __uint_as_float(bb & 0xffff0000u);
          l8[e] = (u16)f32_to_bf16_rne(rem);
        }
        int sl = (((akoff >> 3) + g) ^ (arow & 7)) * 8;
        *(us8*)&Ash[(size_t)arow * 64 + sl] = h8;
        *(us8*)&Ash[(size_t)(128 + arow) * 64 + sl] = l8;
      }
    }
    {
      const f32* src = W + (size_t)(kk * 64 + bkoff) * G3 + n0 + bcol;
#pragma unroll
      for (int g = 0; g < 4; g++) {
        us8 h8, l8;
#pragma unroll
        for (int e = 0; e < 8; e++) {
          f32 v = src[(size_t)(g * 8 + e) * G3];
          u32 bb = __float_as_uint(v);
          h8[e] = (u16)(bb >> 16);
          f32 rem = v - __uint_as_float(bb & 0xffff0000u);
          l8[e] = (u16)f32_to_bf16_rne(rem);
        }
        int sl = (((bkoff >> 3) + g) ^ (bcol & 7)) * 8;
        *(us8*)&Bsh[(size_t)bcol * 64 + sl] = h8;
        *(us8*)&Bsh[(size_t)(128 + bcol) * 64 + sl] = l8;
      }
    }
    __syncthreads();
#pragma unroll
    for (int ks = 0; ks < 2; ks++) {
      F8 ah[2], al[2];
#pragma unroll
      for (int mi = 0; mi < 2; mi++) {
        int row = wv * 32 + mi * 16 + (lane & 15);
        int sl = ((ks * 4 + (lane >> 4)) ^ (row & 7)) * 8;
        ah[mi].u = *(const us8*)&Ash[(size_t)row * 64 + sl];
        al[mi].u = *(const us8*)&Ash[(size_t)(128 + row) * 64 + sl];
      }
#pragma unroll
      for (int ni = 0; ni < 8; ni++) {
        int col = ni * 16 + (lane & 15);
        int sl = ((ks * 4 + (lane >> 4)) ^ (col & 7)) * 8;
        F8 bh, bl;
        bh.u = *(const us8*)&Bsh[(size_t)col * 64 + sl];
        bl.u = *(const us8*)&Bsh[(size_t)(128 + col) * 64 + sl];
#pragma unroll
        for (int mi = 0; mi < 2; mi++) {
          acc[mi][ni] = __builtin_amdgcn_mfma_f32_16x16x32_bf16(ah[mi].b, bh.b, acc[mi][ni], 0, 0, 0);
          acc[mi][ni] = __builtin_amdgcn_mfma_f32_16x16x32_bf16(ah[mi].b, bl.b, acc[mi][ni], 0, 0, 0);
          acc[mi][ni] = __builtin_amdgcn_mfma_f32_16x16x32_bf16(al[mi].b, bh.b, acc[mi][ni], 0, 0, 0);
        }
      }
    }
  }
#pragma unroll
  for (int ni = 0; ni < 8; ni++) {
    int ncol = n0 + ni * 16 + (lane & 15);
    f32 bv = bi[ncol];
#pragma unroll
    for (int mi = 0; mi < 2; mi++) {
#pragma unroll
      for (int j = 0; j < 4; j++) {
        int row = wv * 32 + mi * 16 + (lane >> 4) * 4 + j;
        int srow = s0 + (row >> 6);
        int b = row & 63;
        XG[((size_t)(dir * T_LEN + srow) * B_SZ + b) * G3 + ncol] =
            __float2bfloat16(acc[mi][ni][j] + bv);
      }
    }
  }
}

// ---------------- one recurrence step (round-2 structure), launched 128x ----------------
// 256 blocks (dir x 128 u-slices of 8) x 512 threads (8 waves: 4 b-tiles x 2 k-halves).
// H packed u32 [k][b]; plain rolled K-loop, compiler-scheduled loads (NO manual prefetch).
__global__ __launch_bounds__(512) void gru_step5(
    const u16* __restrict__ USW,
    u32* __restrict__ Hq,            // [2 buf][2 dir][1024 k][64 b] packed (hi | lo<<16)
    const u16* __restrict__ XG,      // bf16 bits [2][128][64 b][3072 col]
    const f32* __restrict__ bhf, const f32* __restrict__ bhb,
    f32* __restrict__ out, int s)
{
  extern __shared__ u16 Us[];        // [2][24][1024] swizzled (96 KB); red aliases it
  const int blk = blockIdx.x;
  const int dir = blk >> 7;
  const int su  = (blk & 127) * 8;
  const int tid = threadIdx.x;
  const int lane = tid & 63;
  const int w  = tid >> 6;
  const int nw = w & 3, kw = w >> 2;

  // stage per-block U image (swizzle baked into global layout)
  {
    const us8* src = (const us8*)(USW + (size_t)blk * (2 * 24 * 1024));
    us8* dst = (us8*)Us;
    for (int i = tid; i < 6144; i += 512) dst[i] = src[i];
  }

  const u32* Hin  = Hq + (size_t)((s & 1) * 2 + dir) * (U_DIM * B_SZ);
  u32*       Hout = Hq + (size_t)(((s + 1) & 1) * 2 + dir) * (U_DIM * B_SZ);

  const int bb = nw * 16 + (lane & 15);
  const int ko = (lane >> 4) * 8;
  const int r0 = lane & 15;
  const int r1t = 16 + (lane & 15);
  const int r1 = r1t > 23 ? 23 : r1t;   // clamped rows land only in unread output rows

  const int rb_h0 = (0 * 24 + r0) * 2048;
  const int rb_l0 = (1 * 24 + r0) * 2048;
  const int rb_h1 = (0 * 24 + r1) * 2048;
  const int rb_l1 = (1 * 24 + r1) * 2048;
  const int sw0 = r0 & 7, sw1 = r1 & 7;

  __syncthreads();

  f32x4 acc0 = {0.f, 0.f, 0.f, 0.f};
  f32x4 acc1 = {0.f, 0.f, 0.f, 0.f};

  if (s) {
    for (int ks = 0; ks < 16; ks++) {
      const int kb = kw * 512 + ks * 32;
      const int slot = (kb >> 3) + (lane >> 4);
      F8 ah0, al0, ah1, al1;
      ah0.u = *(const us8*)((const char*)Us + rb_h0 + ((slot ^ sw0) << 4));
      al0.u = *(const us8*)((const char*)Us + rb_l0 + ((slot ^ sw0) << 4));
      ah1.u = *(const us8*)((const char*)Us + rb_h1 + ((slot ^ sw1) << 4));
      al1.u = *(const us8*)((const char*)Us + rb_l1 + ((slot ^ sw1) << 4));

      const int kbase = kb + ko;
      u32 wd[8];
#pragma unroll
      for (int e = 0; e < 8; e++) wd[e] = Hin[(size_t)(kbase + e) * B_SZ + bb];
      F8 bh_hi, bh_lo;
#pragma unroll
      for (int e = 0; e < 8; e++) {
        bh_hi.u[e] = (u16)(wd[e] & 0xffffu);
        bh_lo.u[e] = (u16)(wd[e] >> 16);
      }
      acc0 = __builtin_amdgcn_mfma_f32_16x16x32_bf16(ah0.b, bh_hi.b, acc0, 0, 0, 0);
      acc0 = __builtin_amdgcn_mfma_f32_16x16x32_bf16(ah0.b, bh_lo.b, acc0, 0, 0, 0);
      acc0 = __builtin_amdgcn_mfma_f32_16x16x32_bf16(al0.b, bh_hi.b, acc0, 0, 0, 0);
      acc1 = __builtin_amdgcn_mfma_f32_16x16x32_bf16(ah1.b, bh_hi.b, acc1, 0, 0, 0);
      acc1 = __builtin_amdgcn_mfma_f32_16x16x32_bf16(ah1.b, bh_lo.b, acc1, 0, 0, 0);
      acc1 = __builtin_amdgcn_mfma_f32_16x16x32_bf16(al1.b, bh_hi.b, acc1, 0, 0, 0);
    }
  }

  // k-half reduction through LDS (reuse staging area — all Us reads done this launch)
  __syncthreads();
  f32* red = (f32*)Us;               // [4][64][8]
  if (kw == 1) {
    f32* p = red + (size_t)(nw * 64 + lane) * 8;
    *(f32x4*)p = acc0;
    *(f32x4*)(p + 4) = acc1;
  }
  __syncthreads();
  if (kw == 0) {
    const f32* p = red + (size_t)(nw * 64 + lane) * 8;
    f32x4 o0 = *(const f32x4*)p;
    f32x4 o1 = *(const f32x4*)(p + 4);
#pragma unroll
    for (int i = 0; i < 4; i++) { acc0[i] += o0[i]; acc1[i] += o1[i]; }

    f32 racc[4];
#pragma unroll
    for (int j = 0; j < 4; j++) racc[j] = __shfl_xor(acc0[j], 32);   // r-gate rows (8..15)

    if (lane < 32) {
      const int ul0 = (lane >> 4) * 4;     // 0 or 4
      const int u0 = su + ul0;
      const u16* xgp = XG + ((size_t)(dir * T_LEN + s) * B_SZ + bb) * G3;
      us4 gz = *(const us4*)(xgp + u0);
      us4 gr = *(const us4*)(xgp + 1024 + u0);
      us4 gh = *(const us4*)(xgp + 2048 + u0);
      const f32* bh = dir ? bhb : bhf;
      f32x4 hnv;
#pragma unroll
      for (int j = 0; j < 4; j++) {
        const int u = u0 + j;
        f32 hz = acc0[j] + bh[u];
        f32 hr = racc[j] + bh[1024 + u];
        f32 hh = acc1[j] + bh[2048 + u];
        f32 xz = __uint_as_float((u32)gz[j] << 16);
        f32 xr = __uint_as_float((u32)gr[j] << 16);
        f32 xh = __uint_as_float((u32)gh[j] << 16);

        u32 hw = s ? Hin[(size_t)u * B_SZ + bb] : 0u;
        f32 hold = __uint_as_float(hw << 16) + __uint_as_float(hw & 0xffff0000u);

        f32 z  = 1.f / (1.f + expf(-(xz + hz)));
        f32 r  = 1.f / (1.f + expf(-(xr + hr)));
        f32 hc = tanhf(xh + r * hh);
        f32 hnew = z * hold + (1.f - z) * hc;

        u32 hib = f32_to_bf16_rne(hnew);
        f32 rem = hnew - __uint_as_float(hib << 16);
        u32 lob = f32_to_bf16_rne(rem);
        Hout[(size_t)u * B_SZ + bb] = hib | (lob << 16);
        hnv[j] = hnew;
      }

      const int t = dir ? (T_LEN - 1 - s) : s;
      f32* op = out + ((size_t)bb * T_LEN + t) * U_DIM + u0;
      if (s < 64) {
        *(f32x4*)op = hnv;
      } else {
        f32x4 prev = *(const f32x4*)op;
#pragma unroll
        for (int j = 0; j < 4; j++) prev[j] += hnv[j];
        *(f32x4*)op = prev;
      }
      if (s == T_LEN - 1)
        *(f32x4*)(out + (size_t)BTU + (size_t)bb * 2048 + dir * 1024 + u0) = hnv;
    }
  }
}

extern "C" void kernel_launch(void* const* d_in, const int* in_sizes, int n_in,
                              void* d_out, int out_size, void* d_ws, size_t ws_size,
                              hipStream_t stream) {
  (void)in_sizes; (void)n_in; (void)out_size; (void)ws_size;
  const int* tokens = (const int*)d_in[0];
  const f32* emb = (const f32*)d_in[1];
  const f32* Wf  = (const f32*)d_in[2];
  const f32* Uf  = (const f32*)d_in[3];
  const f32* bif = (const f32*)d_in[4];
  const f32* bhf = (const f32*)d_in[5];
  const f32* Wb  = (const f32*)d_in[6];
  const f32* Ub  = (const f32*)d_in[7];
  const f32* bib = (const f32*)d_in[8];
  const f32* bhb = (const f32*)d_in[9];

  char* ws = (char*)d_ws;
  u16*  USW = (u16*)(ws + WS_USW);
  u32*  Hq  = (u32*)(ws + WS_HQ);
  bf16* XG  = (bf16*)(ws + WS_XG);
  f32*  out = (f32*)d_out;

  transpose_split<<<dim3(96, 32, 2), 256, 0, stream>>>(Uf, Ub, USW);

  hipFuncSetAttribute((const void*)xg_gemm_mfma,
                      hipFuncAttributeMaxDynamicSharedMemorySize, XG_LDS);
  xg_gemm_mfma<<<dim3(24, 128), 256, XG_LDS, stream>>>(tokens, emb, Wf, bif, Wb, bib, XG);

  hipFuncSetAttribute((const void*)gru_step5,
                      hipFuncAttributeMaxDynamicSharedMemorySize, STEP_LDS);
  for (int s = 0; s < T_LEN; s++)
    gru_step5<<<256, 512, STEP_LDS, stream>>>(USW, Hq, (const u16*)XG, bhf, bhb, out, s);
}